// Round 6
// baseline (119.996 us; speedup 1.0000x reference)
//
#include <hip/hip_runtime.h>
#include <hip/hip_cooperative_groups.h>
#include <math.h>

namespace cg = cooperative_groups;

#define NSH 27
#define CTR 13
#define KFIX 9
#define CAP 2048      // dense candidate list capacity (fallback select kernel)
#define CHUNK 256     // per-block compaction chunk (fallback prep kernel)
#define CHUNK2 512    // coop kernel chunk size (== its block size)

// Monotone map f32 -> u32 so unsigned compare == float compare, then pack
// (key, idx) into u64: min over packed = lexicographic (d2 asc, idx asc),
// exactly jax.lax.top_k's tie-break (lower index first).
__device__ __forceinline__ unsigned long long packKey(float d, int idx) {
    unsigned int b = __float_as_uint(d);
    unsigned int key = (b & 0x80000000u) ? ~b : (b | 0x80000000u);
    return ((unsigned long long)key << 32) | (unsigned int)idx;
}

__device__ __forceinline__ void cell_setup(const float* __restrict__ cell,
                                           float (*sh_disp)[3], float (*sh_inv)[3],
                                           float* sh_margin) {
    float c[3][3];
    for (int r = 0; r < 3; ++r)
        for (int d = 0; d < 3; ++d) c[r][d] = cell[r*3+d];
    float rn[3];
    for (int r = 0; r < 3; ++r) {
        float s = c[r][0]*c[r][0];
        s += c[r][1]*c[r][1];
        s += c[r][2]*c[r][2];
        rn[r] = sqrtf(s);
    }
    float dx = 0.1f * fminf(rn[0], fminf(rn[1], rn[2]));
    for (int r = 0; r < 3; ++r) sh_margin[r] = dx / rn[r];
    double a00=c[0][0],a01=c[0][1],a02=c[0][2];
    double a10=c[1][0],a11=c[1][1],a12=c[1][2];
    double a20=c[2][0],a21=c[2][1],a22=c[2][2];
    double det = a00*(a11*a22-a12*a21) - a01*(a10*a22-a12*a20)
               + a02*(a10*a21-a11*a20);
    double id = 1.0/det;
    sh_inv[0][0]=(float)((a11*a22-a12*a21)*id);
    sh_inv[0][1]=(float)((a02*a21-a01*a22)*id);
    sh_inv[0][2]=(float)((a01*a12-a02*a11)*id);
    sh_inv[1][0]=(float)((a12*a20-a10*a22)*id);
    sh_inv[1][1]=(float)((a00*a22-a02*a20)*id);
    sh_inv[1][2]=(float)((a02*a10-a00*a12)*id);
    sh_inv[2][0]=(float)((a10*a21-a11*a20)*id);
    sh_inv[2][1]=(float)((a01*a20-a00*a21)*id);
    sh_inv[2][2]=(float)((a00*a11-a01*a10)*id);
    for (int s = 0; s < NSH; ++s) {
        int ix = s/9 - 1, iy = (s/3)%3 - 1, iz = s%3 - 1;
        for (int d = 0; d < 3; ++d) {
            float v = (float)ix * c[0][d];
            v += (float)iy * c[1][d];
            v += (float)iz * c[2][d];
            sh_disp[s][d] = v;
        }
    }
}

// ======== Single cooperative kernel: build + fill | grid.sync | select ======
__global__ void __launch_bounds__(512) coop_kernel(
    const float* __restrict__ pos, const float* __restrict__ cell,
    const int* __restrict__ numbers, float* __restrict__ out,
    int* __restrict__ cnts, float4* __restrict__ chunks, int N, int nblocks)
{
    __shared__ float sh_disp[NSH][3];
    __shared__ float sh_inv[3][3];
    __shared__ float sh_margin[3];
    __shared__ int wcnt[8];
    __shared__ int pref[NSH + 1];

    const int tid  = threadIdx.x;
    const int bid  = blockIdx.x;
    const int lane = tid & 63;
    const int wid  = tid >> 6;

    if (tid == 0) cell_setup(cell, sh_disp, sh_inv, sh_margin);
    __syncthreads();

    const int Ns  = NSH * N;                 // == NSH * CHUNK2 on this path
    const int NsK = Ns * KFIX;

    // ---- build: block bid < NSH compacts points [bid*512, bid*512+512) ----
    if (bid < NSH) {
        const int j = bid * CHUNK2 + tid;
        int aj = j % N, cj = j / N;
        float x = pos[aj*3+0] + sh_disp[cj][0];
        float y = pos[aj*3+1] + sh_disp[cj][1];
        float z = pos[aj*3+2] + sh_disp[cj][2];
        bool vj = true;
        for (int d = 0; d < 3; ++d) {
            float f = x*sh_inv[0][d];
            f += y*sh_inv[1][d];
            f += z*sh_inv[2][d];
            float m = sh_margin[d];
            vj = vj && (f >= -m) && (f <= 1.0f + m);
        }
        unsigned long long mask = __ballot(vj);
        int within = __popcll(mask & ((1ull << lane) - 1ull));
        if (lane == 0) wcnt[wid] = __popcll(mask);
        __syncthreads();
        int base = 0;
        for (int w = 0; w < wid; ++w) base += wcnt[w];
        if (vj)
            chunks[bid * CHUNK2 + base + within] =
                make_float4(x, y, z, __int_as_float(j));
        if (tid == 0) {
            int t = 0;
            for (int w = 0; w < 8; ++w) t += wcnt[w];
            cnts[bid] = t;
        }
    }

    // ---- fill: unconditional defaults (select overwrites valid rows) ----
    float* oD  = out;
    float* oSA = out +     NsK;
    float* oDA = out + 2LL*NsK;
    float* oSC = out + 3LL*NsK;
    float* oEV = out + 4LL*NsK;
    float* oNS = out + 5LL*NsK;
    {
        const int gthreads = nblocks * 512;
        const int gt = bid * 512 + tid;
        for (int e = gt; e < NsK; e += gthreads) {
            int row = e / KFIX;
            int s   = e - row * KFIX;
            oD[e]  = sqrtf(1e30f);
            oSA[e] = (float)(s % N);
            oDA[e] = (float)(row % N);
            oSC[e] = (float)(s / N);
            oEV[e] = 0.0f;
        }
        for (int e = gt; e < Ns; e += gthreads) oNS[e] = (float)numbers[e % N];
    }

    __threadfence();
    cg::this_grid().sync();

    // ---- select: dense candidate index i -> one wave each ----
    if (wid == 0) {                  // wave-0 inclusive scan of chunk counts
        int c = (lane < NSH) ? cnts[lane] : 0;
        int s = c;
        #pragma unroll
        for (int off = 1; off < 64; off <<= 1) {
            int o = __shfl_up(s, off, 64);
            if (lane >= off) s += o;
        }
        if (lane < NSH) pref[lane + 1] = s;
        if (lane == 0)  pref[0] = 0;
    }
    __syncthreads();
    const int M = pref[NSH];

    const int gwaves = nblocks * 8;
    const unsigned long long UMAX = 0xFFFFFFFFFFFFFFFFull;

    for (int i = bid * 8 + wid; i < M; i += gwaves) {
        // locate dense index i -> (chunk c0, offset)
        int c0 = 0;
        while (pref[c0 + 1] <= i) ++c0;
        const float4 me = chunks[c0 * CHUNK2 + (i - pref[c0])];
        const int row = __float_as_int(me.w);
        const int a_i = row % N;
        const int c_i = row / N;
        float sqi = me.x*me.x; sqi += me.y*me.y; sqi += me.z*me.z;

        unsigned long long lst[KFIX];
        #pragma unroll
        for (int q = 0; q < KFIX; ++q) lst[q] = UMAX;

        for (int c = 0; c < NSH; ++c) {
            const int b  = pref[c];
            const int cc = pref[c + 1] - b;
            for (int t = lane; t < cc; t += 64) {
                float4 cd = chunks[c * CHUNK2 + t];
                float sqj = cd.x*cd.x; sqj += cd.y*cd.y; sqj += cd.z*cd.z;
                float dot = me.x*cd.x; dot += me.y*cd.y; dot += me.z*cd.z;
                float d2 = (sqi + sqj) - 2.0f*dot;
                unsigned long long key = packKey(d2, __float_as_int(cd.w));
                if (key < lst[KFIX-1]) {
                    lst[KFIX-1] = key;
                    #pragma unroll
                    for (int q = KFIX-1; q > 0; --q) {
                        unsigned long long a = lst[q-1], bb = lst[q];
                        lst[q-1] = a < bb ? a : bb;
                        lst[q]   = a < bb ? bb : a;
                    }
                }
            }
        }

        // merge 64 sorted lists: k rounds of wave-wide min over heads
        unsigned long long mine = UMAX;
        #pragma unroll
        for (int s = 0; s < KFIX; ++s) {
            unsigned long long b = lst[0];
            #pragma unroll
            for (int off = 1; off < 64; off <<= 1) {
                unsigned long long o = __shfl_xor(b, off, 64);
                b = o < b ? o : b;
            }
            if (lst[0] == b) {        // unique: idx in low bits
                #pragma unroll
                for (int q = 0; q < KFIX-1; ++q) lst[q] = lst[q+1];
                lst[KFIX-1] = UMAX;
            }
            if (lane == s) mine = b;
        }

        if (lane < KFIX) {
            int bj = (int)(mine & 0xFFFFFFFFull);
            unsigned int kb = (unsigned int)(mine >> 32);
            unsigned int fb = (kb & 0x80000000u) ? (kb & 0x7FFFFFFFu) : ~kb;
            float d2v = __uint_as_float(fb);
            int e = row * KFIX + lane;
            oD[e]  = sqrtf(fmaxf(d2v, 1e-12f));
            oSA[e] = (float)(bj % N);
            oDA[e] = (float)a_i;
            oSC[e] = (float)(bj / N);
            oEV[e] = (d2v < 1e30f && c_i == CTR) ? 1.0f : 0.0f;
        }
    }
}

// ---- K1 (fallback): deterministic chunk compaction + default fill ----
__global__ void __launch_bounds__(256) prep_kernel(
    const float* __restrict__ pos, const float* __restrict__ cell,
    const int* __restrict__ numbers, float* __restrict__ out,
    int* __restrict__ cnts, float4* __restrict__ chunks, int N, int nch)
{
    __shared__ float sh_disp[NSH][3];
    __shared__ float sh_inv[3][3];
    __shared__ float sh_margin[3];
    __shared__ int wtot[4];
    const int tid = threadIdx.x;
    if (tid == 0) cell_setup(cell, sh_disp, sh_inv, sh_margin);
    __syncthreads();

    const int Ns  = NSH * N;
    const int NsK = Ns * KFIX;

    if ((int)blockIdx.x < nch) {
        const int j = blockIdx.x * CHUNK + tid;
        bool vj = false;
        float x = 0.f, y = 0.f, z = 0.f;
        if (j < Ns) {
            int aj = j % N, cj = j / N;
            x = pos[aj*3+0] + sh_disp[cj][0];
            y = pos[aj*3+1] + sh_disp[cj][1];
            z = pos[aj*3+2] + sh_disp[cj][2];
            vj = true;
            for (int d = 0; d < 3; ++d) {
                float f = x*sh_inv[0][d];
                f += y*sh_inv[1][d];
                f += z*sh_inv[2][d];
                float m = sh_margin[d];
                vj = vj && (f >= -m) && (f <= 1.0f + m);
            }
        }
        const int lane = tid & 63, wid = tid >> 6;
        unsigned long long mask = __ballot(vj);
        int within = __popcll(mask & ((1ull << lane) - 1ull));
        if (lane == 0) wtot[wid] = __popcll(mask);
        __syncthreads();
        int base = 0;
        for (int w = 0; w < wid; ++w) base += wtot[w];
        if (vj)
            chunks[blockIdx.x * CHUNK + base + within] =
                make_float4(x, y, z, __int_as_float(j));
        if (tid == 0)
            cnts[blockIdx.x] = wtot[0] + wtot[1] + wtot[2] + wtot[3];
    }

    const int gthreads = gridDim.x * blockDim.x;
    const int gt = blockIdx.x * blockDim.x + tid;
    float* oD  = out;
    float* oSA = out +     NsK;
    float* oDA = out + 2LL*NsK;
    float* oSC = out + 3LL*NsK;
    float* oEV = out + 4LL*NsK;
    float* oNS = out + 5LL*NsK;
    for (int e = gt; e < NsK; e += gthreads) {
        int row = e / KFIX;
        int s   = e - row * KFIX;
        oD[e]  = sqrtf(1e30f);
        oSA[e] = (float)(s % N);
        oDA[e] = (float)(row % N);
        oSC[e] = (float)(s / N);
        oEV[e] = 0.0f;
    }
    for (int e = gt; e < Ns; e += gthreads) oNS[e] = (float)numbers[e % N];
}

// ---- K2 (fallback): dense LDS list + one wave per valid row, top-9 ----
__global__ void __launch_bounds__(256) select_kernel(
    float* __restrict__ out,
    const int* __restrict__ cnts, const float4* __restrict__ chunks,
    int N, int nch)
{
    __shared__ float4 list[CAP];
    __shared__ int pref[65];
    const int tid  = threadIdx.x;
    const int lane = tid & 63;
    const int wid  = tid >> 6;
    const int Ns   = NSH * N;

    if (wid == 0) {
        int c = (lane < nch) ? cnts[lane] : 0;
        int s = c;
        #pragma unroll
        for (int off = 1; off < 64; off <<= 1) {
            int o = __shfl_up(s, off, 64);
            if (lane >= off) s += o;
        }
        pref[lane + 1] = s;
        if (lane == 0) pref[0] = 0;
    }
    __syncthreads();
    const int Mfull = pref[nch];
    const int M = Mfull < CAP ? Mfull : CAP;
    if ((int)blockIdx.x * 4 >= M) return;

    for (int c = wid; c < nch; c += 4) {
        int b = pref[c];
        int cc = pref[c + 1] - b;
        for (int t = lane; t < cc; t += 64)
            if (b + t < CAP) list[b + t] = chunks[c * CHUNK + t];
    }
    __syncthreads();

    const int i = blockIdx.x * 4 + wid;
    if (i >= M) return;

    const float4 me = list[i];
    const int row = __float_as_int(me.w);
    const int a_i = row % N;
    const int c_i = row / N;
    float sqi = me.x*me.x; sqi += me.y*me.y; sqi += me.z*me.z;

    const unsigned long long UMAX = 0xFFFFFFFFFFFFFFFFull;
    unsigned long long lst[KFIX];
    #pragma unroll
    for (int q = 0; q < KFIX; ++q) lst[q] = UMAX;

    for (int j = lane; j < M; j += 64) {
        float4 c = list[j];
        float sqj = c.x*c.x; sqj += c.y*c.y; sqj += c.z*c.z;
        float dot = me.x*c.x; dot += me.y*c.y; dot += me.z*c.z;
        float d2 = (sqi + sqj) - 2.0f*dot;
        unsigned long long key = packKey(d2, __float_as_int(c.w));
        if (key < lst[KFIX-1]) {
            lst[KFIX-1] = key;
            #pragma unroll
            for (int q = KFIX-1; q > 0; --q) {
                unsigned long long a = lst[q-1], b = lst[q];
                lst[q-1] = a < b ? a : b;
                lst[q]   = a < b ? b : a;
            }
        }
    }

    unsigned long long mine = UMAX;
    #pragma unroll
    for (int s = 0; s < KFIX; ++s) {
        unsigned long long b = lst[0];
        #pragma unroll
        for (int off = 1; off < 64; off <<= 1) {
            unsigned long long o = __shfl_xor(b, off, 64);
            b = o < b ? o : b;
        }
        if (lst[0] == b) {
            #pragma unroll
            for (int q = 0; q < KFIX-1; ++q) lst[q] = lst[q+1];
            lst[KFIX-1] = UMAX;
        }
        if (lane == s) mine = b;
    }

    if (lane < KFIX) {
        const int NsK = Ns * KFIX;
        float* oD  = out;
        float* oSA = out +     NsK;
        float* oDA = out + 2LL*NsK;
        float* oSC = out + 3LL*NsK;
        float* oEV = out + 4LL*NsK;
        int bj = (int)(mine & 0xFFFFFFFFull);
        unsigned int kb = (unsigned int)(mine >> 32);
        unsigned int fb = (kb & 0x80000000u) ? (kb & 0x7FFFFFFFu) : ~kb;
        float d2v = __uint_as_float(fb);
        int e = row * KFIX + lane;
        oD[e]  = sqrtf(fmaxf(d2v, 1e-12f));
        oSA[e] = (float)(bj % N);
        oDA[e] = (float)a_i;
        oSC[e] = (float)(bj / N);
        oEV[e] = (d2v < 1e30f && c_i == CTR) ? 1.0f : 0.0f;
    }
}

// ---------------- Fallback: round-1 monolithic kernel (k != 9) ----------------
__global__ void __launch_bounds__(256) knn_kernel(
    const float* __restrict__ pos, const float* __restrict__ cell,
    const int* __restrict__ numbers, const int* __restrict__ kptr,
    float* __restrict__ out, int N)
{
    extern __shared__ float d2row[];
    const int Ns  = NSH * N;
    const int k   = kptr[0];
    const int row = blockIdx.x;
    const int tid = threadIdx.x;
    const int nthr = blockDim.x;

    __shared__ float sh_disp[NSH][3];
    __shared__ float sh_inv[3][3];
    __shared__ float sh_margin[3];
    __shared__ unsigned long long sh_wmin[4];

    if (tid == 0) cell_setup(cell, sh_disp, sh_inv, sh_margin);
    __syncthreads();

    const int a_i = row % N;
    const int c_i = row / N;
    const float pix = pos[a_i*3+0] + sh_disp[c_i][0];
    const float piy = pos[a_i*3+1] + sh_disp[c_i][1];
    const float piz = pos[a_i*3+2] + sh_disp[c_i][2];
    float sqi = pix*pix; sqi += piy*piy; sqi += piz*piz;

    bool vi = true;
    for (int d = 0; d < 3; ++d) {
        float f = pix*sh_inv[0][d];
        f += piy*sh_inv[1][d];
        f += piz*sh_inv[2][d];
        float m = sh_margin[d];
        vi = vi && (f >= -m) && (f <= 1.0f + m);
    }

    const long long NsK = (long long)Ns * (long long)k;
    float* oD  = out;
    float* oSA = out +     NsK;
    float* oDA = out + 2LL*NsK;
    float* oSC = out + 3LL*NsK;
    float* oEV = out + 4LL*NsK;
    float* oNS = out + 5LL*NsK;

    if (tid == 0) oNS[row] = (float)numbers[a_i];

    if (!vi) {
        if (tid < k) {
            long long e = (long long)row * k + tid;
            oD[e]  = sqrtf(1e30f);
            oSA[e] = (float)(tid % N);
            oDA[e] = (float)a_i;
            oSC[e] = (float)(tid / N);
            oEV[e] = 0.0f;
        }
        return;
    }

    {
        int aj = tid % N;
        int cj = tid / N;
        for (int j = tid; j < Ns; j += nthr) {
            float px = pos[aj*3+0] + sh_disp[cj][0];
            float py = pos[aj*3+1] + sh_disp[cj][1];
            float pz = pos[aj*3+2] + sh_disp[cj][2];
            float sqj = px*px; sqj += py*py; sqj += pz*pz;
            bool vj = true;
            for (int d = 0; d < 3; ++d) {
                float f = px*sh_inv[0][d];
                f += py*sh_inv[1][d];
                f += pz*sh_inv[2][d];
                float m = sh_margin[d];
                vj = vj && (f >= -m) && (f <= 1.0f + m);
            }
            float dot = pix*px; dot += piy*py; dot += piz*pz;
            float d2 = (sqi + sqj) - 2.0f*dot;
            d2row[j] = vj ? d2 : 1e30f;
            aj += nthr;
            while (aj >= N) { aj -= N; ++cj; }
        }
    }
    __syncthreads();

    const int lane = tid & 63;
    const int wid  = tid >> 6;
    const int nw   = nthr >> 6;

    for (int s = 0; s < k; ++s) {
        unsigned long long best = 0xFFFFFFFFFFFFFFFFull;
        for (int j = tid; j < Ns; j += nthr) {
            unsigned long long key = packKey(d2row[j], j);
            best = key < best ? key : best;
        }
        for (int off = 32; off > 0; off >>= 1) {
            unsigned long long o = __shfl_down(best, off, 64);
            best = o < best ? o : best;
        }
        if (lane == 0) sh_wmin[wid] = best;
        __syncthreads();
        if (tid == 0) {
            unsigned long long b = sh_wmin[0];
            for (int w = 1; w < nw; ++w) {
                unsigned long long o = sh_wmin[w];
                b = o < b ? o : b;
            }
            int bj = (int)(b & 0xFFFFFFFFull);
            d2row[bj] = INFINITY;
            unsigned int kb = (unsigned int)(b >> 32);
            unsigned int fb = (kb & 0x80000000u) ? (kb & 0x7FFFFFFFu) : ~kb;
            float d2v = __uint_as_float(fb);
            long long e = (long long)row * k + s;
            oD[e]  = sqrtf(fmaxf(d2v, 1e-12f));
            oSA[e] = (float)(bj % N);
            oDA[e] = (float)a_i;
            oSC[e] = (float)(bj / N);
            oEV[e] = (d2v < 1e30f && c_i == CTR) ? 1.0f : 0.0f;
        }
        __syncthreads();
    }
}

extern "C" void kernel_launch(void* const* d_in, const int* in_sizes, int n_in,
                              void* d_out, int out_size, void* d_ws, size_t ws_size,
                              hipStream_t stream) {
    const float* pos     = (const float*)d_in[0];   // [N,3] f32
    const float* cell    = (const float*)d_in[1];   // [3,3] f32
    const int*   numbers = (const int*)d_in[2];     // [N]   i32
    const int*   kptr    = (const int*)d_in[3];     // scalar i32
    float* out = (float*)d_out;

    int N  = in_sizes[0] / 3;
    const int Ns = NSH * N;
    // out layout: 5 sections of [Ns,k] + [Ns]  ->  k derivable on host
    const int k   = (out_size / Ns - 1) / 5;
    const int nch = (Ns + CHUNK - 1) / CHUNK;

    const size_t needCoop = 256 + (size_t)NSH * CHUNK2 * sizeof(float4);
    const size_t needFb   = 256 + (size_t)nch * CHUNK * sizeof(float4);

    if (k == KFIX && N == CHUNK2 && ws_size >= needCoop) {
        int*    cnts   = (int*)d_ws;
        float4* chunks = (float4*)((char*)d_ws + 256);
        int nblocks = 256;
        void* args[] = { (void*)&pos, (void*)&cell, (void*)&numbers,
                         (void*)&out, (void*)&cnts, (void*)&chunks,
                         (void*)&N, (void*)&nblocks };
        hipError_t err = hipLaunchCooperativeKernel(
            (const void*)coop_kernel, dim3(nblocks), dim3(512), args, 0, stream);
        if (err == hipSuccess) return;
        // fall through to two-kernel path on any failure
    }

    if (k == KFIX && nch <= 64 && ws_size >= needFb) {
        int*    cnts   = (int*)d_ws;
        float4* chunks = (float4*)((char*)d_ws + 256);
        prep_kernel<<<256, 256, 0, stream>>>(
            pos, cell, numbers, out, cnts, chunks, N, nch);
        select_kernel<<<512, 256, 0, stream>>>(out, cnts, chunks, N, nch);
    } else {
        const size_t shbytes = (size_t)Ns * sizeof(float);
        knn_kernel<<<Ns, 256, shbytes, stream>>>(pos, cell, numbers, kptr, out, N);
    }
}

// Round 7
// 20.376 us; speedup vs baseline: 5.8890x; 5.8890x over previous
//
#include <hip/hip_runtime.h>
#include <math.h>

#define NSH 27
#define CTR 13
#define KFIX 9
#define NFIX 512      // fused path requires N == 512 (bench shape)
#define CAPF 2048     // fused LDS candidate capacity (expected M ~ 885)
#define CAP 2048      // fallback dense list capacity
#define CHUNK 256     // fallback per-block compaction chunk

// Monotone map f32 -> u32 so unsigned compare == float compare, then pack
// (key, idx) into u64: min over packed = lexicographic (d2 asc, idx asc),
// exactly jax.lax.top_k's tie-break (lower index first).
__device__ __forceinline__ unsigned long long packKey(float d, int idx) {
    unsigned int b = __float_as_uint(d);
    unsigned int key = (b & 0x80000000u) ? ~b : (b | 0x80000000u);
    return ((unsigned long long)key << 32) | (unsigned int)idx;
}

__device__ __forceinline__ void cell_setup(const float* __restrict__ cell,
                                           float (*sh_disp)[3], float (*sh_inv)[3],
                                           float* sh_margin) {
    float c[3][3];
    for (int r = 0; r < 3; ++r)
        for (int d = 0; d < 3; ++d) c[r][d] = cell[r*3+d];
    float rn[3];
    for (int r = 0; r < 3; ++r) {
        float s = c[r][0]*c[r][0];
        s += c[r][1]*c[r][1];
        s += c[r][2]*c[r][2];
        rn[r] = sqrtf(s);
    }
    float dx = 0.1f * fminf(rn[0], fminf(rn[1], rn[2]));
    for (int r = 0; r < 3; ++r) sh_margin[r] = dx / rn[r];
    double a00=c[0][0],a01=c[0][1],a02=c[0][2];
    double a10=c[1][0],a11=c[1][1],a12=c[1][2];
    double a20=c[2][0],a21=c[2][1],a22=c[2][2];
    double det = a00*(a11*a22-a12*a21) - a01*(a10*a22-a12*a20)
               + a02*(a10*a21-a11*a20);
    double id = 1.0/det;
    sh_inv[0][0]=(float)((a11*a22-a12*a21)*id);
    sh_inv[0][1]=(float)((a02*a21-a01*a22)*id);
    sh_inv[0][2]=(float)((a01*a12-a02*a11)*id);
    sh_inv[1][0]=(float)((a12*a20-a10*a22)*id);
    sh_inv[1][1]=(float)((a00*a22-a02*a20)*id);
    sh_inv[1][2]=(float)((a02*a10-a00*a12)*id);
    sh_inv[2][0]=(float)((a10*a21-a11*a20)*id);
    sh_inv[2][1]=(float)((a01*a20-a00*a21)*id);
    sh_inv[2][2]=(float)((a00*a11-a01*a10)*id);
    for (int s = 0; s < NSH; ++s) {
        int ix = s/9 - 1, iy = (s/3)%3 - 1, iz = s%3 - 1;
        for (int d = 0; d < 3; ++d) {
            float v = (float)ix * c[0][d];
            v += (float)iy * c[1][d];
            v += (float)iz * c[2][d];
            sh_disp[s][d] = v;
        }
    }
}

// ===== Single fused kernel (N==512, k==9): ballot build + fill + select =====
__global__ void __launch_bounds__(512) fused1_kernel(
    const float* __restrict__ pos, const float* __restrict__ cell,
    const int* __restrict__ numbers, float* __restrict__ out)
{
    __shared__ float4 list[CAPF];
    __shared__ unsigned int bmask[NFIX];  // bit q of bmask[t]: valid(j=q*512+t)
    __shared__ float sh_disp[NSH][3];
    __shared__ float sh_inv[3][3];
    __shared__ float sh_margin[3];
    __shared__ int wtot[8];

    const int tid  = threadIdx.x;          // == atom id t
    const int lane = tid & 63;
    const int wid  = tid >> 6;

    if (tid == 0) cell_setup(cell, sh_disp, sh_inv, sh_margin);
    __syncthreads();                       // barrier A: cell tables ready

    const int N  = NFIX;
    const int Ns = NSH * N;

    // ---- pass 1: validity bits for this thread's 27 images ----
    const float px = pos[tid*3+0];
    const float py = pos[tid*3+1];
    const float pz = pos[tid*3+2];
    unsigned int mask = 0u;
    for (int q = 0; q < NSH; ++q) {
        float x = px + sh_disp[q][0];
        float y = py + sh_disp[q][1];
        float z = pz + sh_disp[q][2];
        bool vj = true;
        for (int d = 0; d < 3; ++d) {
            float f = x*sh_inv[0][d];
            f += y*sh_inv[1][d];
            f += z*sh_inv[2][d];
            float m = sh_margin[d];
            vj = vj && (f >= -m) && (f <= 1.0f + m);
        }
        if (vj) mask |= (1u << q);
    }
    bmask[tid] = mask;
    const int cntv = __popc(mask);
    int inc = cntv;                        // inclusive lane scan
    #pragma unroll
    for (int off = 1; off < 64; off <<= 1) {
        int o = __shfl_up(inc, off, 64);
        if (lane >= off) inc += o;
    }
    if (lane == 63) wtot[wid] = inc;
    const int excl = inc - cntv;
    __syncthreads();                       // barrier B: wtot + bmask ready

    int wbase = 0;
    for (int w = 0; w < wid; ++w) wbase += wtot[w];
    int M = 0;
    for (int w = 0; w < 8; ++w) M += wtot[w];
    if (M > CAPF) M = CAPF;

    // ---- pass 2: write compacted candidate list (deterministic order) ----
    {
        int off = wbase + excl;
        for (int q = 0; q < NSH; ++q) {
            if (mask & (1u << q)) {
                if (off < CAPF) {
                    float x = px + sh_disp[q][0];
                    float y = py + sh_disp[q][1];
                    float z = pz + sh_disp[q][2];
                    list[off] = make_float4(x, y, z, __int_as_float(q*N + tid));
                }
                ++off;
            }
        }
    }
    __syncthreads();                       // barrier C: list ready

    const int NsK = Ns * KFIX;
    float* oD  = out;
    float* oSA = out +     NsK;
    float* oDA = out + 2LL*NsK;
    float* oSC = out + 3LL*NsK;
    float* oEV = out + 4LL*NsK;
    float* oNS = out + 5LL*NsK;

    // ---- fill: defaults for INVALID rows only (disjoint from select) ----
    {
        const int gthreads = gridDim.x * 512;
        const int gt = blockIdx.x * 512 + tid;
        for (int e = gt; e < NsK; e += gthreads) {
            int row = e / KFIX;
            if (!((bmask[row & 511] >> (row >> 9)) & 1u)) {
                int s = e - row * KFIX;
                oD[e]  = sqrtf(1e30f);
                oSA[e] = (float)(s % N);
                oDA[e] = (float)(row % N);
                oSC[e] = (float)(s / N);
                oEV[e] = 0.0f;
            }
        }
        for (int e = gt; e < Ns; e += gthreads) oNS[e] = (float)numbers[e & 511];
    }

    // ---- select: one wave per valid candidate (dense index) ----
    const int gwaves = gridDim.x * 8;
    const unsigned long long UMAX = 0xFFFFFFFFFFFFFFFFull;

    for (int i = blockIdx.x * 8 + wid; i < M; i += gwaves) {
        const float4 me = list[i];
        const int row = __float_as_int(me.w);
        const int a_i = row % N;
        const int c_i = row / N;
        float sqi = me.x*me.x; sqi += me.y*me.y; sqi += me.z*me.z;

        unsigned long long lst[KFIX];
        #pragma unroll
        for (int q = 0; q < KFIX; ++q) lst[q] = UMAX;

        for (int j = lane; j < M; j += 64) {
            float4 c = list[j];
            float sqj = c.x*c.x; sqj += c.y*c.y; sqj += c.z*c.z;
            float dot = me.x*c.x; dot += me.y*c.y; dot += me.z*c.z;
            float d2 = (sqi + sqj) - 2.0f*dot;
            unsigned long long key = packKey(d2, __float_as_int(c.w));
            if (key < lst[KFIX-1]) {
                lst[KFIX-1] = key;
                #pragma unroll
                for (int q = KFIX-1; q > 0; --q) {
                    unsigned long long a = lst[q-1], b = lst[q];
                    lst[q-1] = a < b ? a : b;
                    lst[q]   = a < b ? b : a;
                }
            }
        }

        // merge 64 sorted lists: k rounds of wave-wide min over heads
        unsigned long long mine = UMAX;
        #pragma unroll
        for (int s = 0; s < KFIX; ++s) {
            unsigned long long b = lst[0];
            #pragma unroll
            for (int off = 1; off < 64; off <<= 1) {
                unsigned long long o = __shfl_xor(b, off, 64);
                b = o < b ? o : b;
            }
            if (lst[0] == b) {             // unique: idx in low bits
                #pragma unroll
                for (int q = 0; q < KFIX-1; ++q) lst[q] = lst[q+1];
                lst[KFIX-1] = UMAX;
            }
            if (lane == s) mine = b;
        }

        if (lane < KFIX) {
            int bj = (int)(mine & 0xFFFFFFFFull);
            unsigned int kb = (unsigned int)(mine >> 32);
            unsigned int fb = (kb & 0x80000000u) ? (kb & 0x7FFFFFFFu) : ~kb;
            float d2v = __uint_as_float(fb);
            int e = row * KFIX + lane;
            oD[e]  = sqrtf(fmaxf(d2v, 1e-12f));
            oSA[e] = (float)(bj % N);
            oDA[e] = (float)a_i;
            oSC[e] = (float)(bj / N);
            oEV[e] = (d2v < 1e30f && c_i == CTR) ? 1.0f : 0.0f;
        }
    }
}

// ---- K1 (fallback): deterministic chunk compaction + default fill ----
__global__ void __launch_bounds__(256) prep_kernel(
    const float* __restrict__ pos, const float* __restrict__ cell,
    const int* __restrict__ numbers, float* __restrict__ out,
    int* __restrict__ cnts, float4* __restrict__ chunks, int N, int nch)
{
    __shared__ float sh_disp[NSH][3];
    __shared__ float sh_inv[3][3];
    __shared__ float sh_margin[3];
    __shared__ int wtot[4];
    const int tid = threadIdx.x;
    if (tid == 0) cell_setup(cell, sh_disp, sh_inv, sh_margin);
    __syncthreads();

    const int Ns  = NSH * N;
    const int NsK = Ns * KFIX;

    if ((int)blockIdx.x < nch) {
        const int j = blockIdx.x * CHUNK + tid;
        bool vj = false;
        float x = 0.f, y = 0.f, z = 0.f;
        if (j < Ns) {
            int aj = j % N, cj = j / N;
            x = pos[aj*3+0] + sh_disp[cj][0];
            y = pos[aj*3+1] + sh_disp[cj][1];
            z = pos[aj*3+2] + sh_disp[cj][2];
            vj = true;
            for (int d = 0; d < 3; ++d) {
                float f = x*sh_inv[0][d];
                f += y*sh_inv[1][d];
                f += z*sh_inv[2][d];
                float m = sh_margin[d];
                vj = vj && (f >= -m) && (f <= 1.0f + m);
            }
        }
        const int lane = tid & 63, wid = tid >> 6;
        unsigned long long mask = __ballot(vj);
        int within = __popcll(mask & ((1ull << lane) - 1ull));
        if (lane == 0) wtot[wid] = __popcll(mask);
        __syncthreads();
        int base = 0;
        for (int w = 0; w < wid; ++w) base += wtot[w];
        if (vj)
            chunks[blockIdx.x * CHUNK + base + within] =
                make_float4(x, y, z, __int_as_float(j));
        if (tid == 0)
            cnts[blockIdx.x] = wtot[0] + wtot[1] + wtot[2] + wtot[3];
    }

    const int gthreads = gridDim.x * blockDim.x;
    const int gt = blockIdx.x * blockDim.x + tid;
    float* oD  = out;
    float* oSA = out +     NsK;
    float* oDA = out + 2LL*NsK;
    float* oSC = out + 3LL*NsK;
    float* oEV = out + 4LL*NsK;
    float* oNS = out + 5LL*NsK;
    for (int e = gt; e < NsK; e += gthreads) {
        int row = e / KFIX;
        int s   = e - row * KFIX;
        oD[e]  = sqrtf(1e30f);
        oSA[e] = (float)(s % N);
        oDA[e] = (float)(row % N);
        oSC[e] = (float)(s / N);
        oEV[e] = 0.0f;
    }
    for (int e = gt; e < Ns; e += gthreads) oNS[e] = (float)numbers[e % N];
}

// ---- K2 (fallback): dense LDS list + one wave per valid row, top-9 ----
__global__ void __launch_bounds__(256) select_kernel(
    float* __restrict__ out,
    const int* __restrict__ cnts, const float4* __restrict__ chunks,
    int N, int nch)
{
    __shared__ float4 list[CAP];
    __shared__ int pref[65];
    const int tid  = threadIdx.x;
    const int lane = tid & 63;
    const int wid  = tid >> 6;
    const int Ns   = NSH * N;

    if (wid == 0) {
        int c = (lane < nch) ? cnts[lane] : 0;
        int s = c;
        #pragma unroll
        for (int off = 1; off < 64; off <<= 1) {
            int o = __shfl_up(s, off, 64);
            if (lane >= off) s += o;
        }
        pref[lane + 1] = s;
        if (lane == 0) pref[0] = 0;
    }
    __syncthreads();
    const int Mfull = pref[nch];
    const int M = Mfull < CAP ? Mfull : CAP;
    if ((int)blockIdx.x * 4 >= M) return;

    for (int c = wid; c < nch; c += 4) {
        int b = pref[c];
        int cc = pref[c + 1] - b;
        for (int t = lane; t < cc; t += 64)
            if (b + t < CAP) list[b + t] = chunks[c * CHUNK + t];
    }
    __syncthreads();

    const int i = blockIdx.x * 4 + wid;
    if (i >= M) return;

    const float4 me = list[i];
    const int row = __float_as_int(me.w);
    const int a_i = row % N;
    const int c_i = row / N;
    float sqi = me.x*me.x; sqi += me.y*me.y; sqi += me.z*me.z;

    const unsigned long long UMAX = 0xFFFFFFFFFFFFFFFFull;
    unsigned long long lst[KFIX];
    #pragma unroll
    for (int q = 0; q < KFIX; ++q) lst[q] = UMAX;

    for (int j = lane; j < M; j += 64) {
        float4 c = list[j];
        float sqj = c.x*c.x; sqj += c.y*c.y; sqj += c.z*c.z;
        float dot = me.x*c.x; dot += me.y*c.y; dot += me.z*c.z;
        float d2 = (sqi + sqj) - 2.0f*dot;
        unsigned long long key = packKey(d2, __float_as_int(c.w));
        if (key < lst[KFIX-1]) {
            lst[KFIX-1] = key;
            #pragma unroll
            for (int q = KFIX-1; q > 0; --q) {
                unsigned long long a = lst[q-1], b = lst[q];
                lst[q-1] = a < b ? a : b;
                lst[q]   = a < b ? b : a;
            }
        }
    }

    unsigned long long mine = UMAX;
    #pragma unroll
    for (int s = 0; s < KFIX; ++s) {
        unsigned long long b = lst[0];
        #pragma unroll
        for (int off = 1; off < 64; off <<= 1) {
            unsigned long long o = __shfl_xor(b, off, 64);
            b = o < b ? o : b;
        }
        if (lst[0] == b) {
            #pragma unroll
            for (int q = 0; q < KFIX-1; ++q) lst[q] = lst[q+1];
            lst[KFIX-1] = UMAX;
        }
        if (lane == s) mine = b;
    }

    if (lane < KFIX) {
        const int NsK = Ns * KFIX;
        float* oD  = out;
        float* oSA = out +     NsK;
        float* oDA = out + 2LL*NsK;
        float* oSC = out + 3LL*NsK;
        float* oEV = out + 4LL*NsK;
        int bj = (int)(mine & 0xFFFFFFFFull);
        unsigned int kb = (unsigned int)(mine >> 32);
        unsigned int fb = (kb & 0x80000000u) ? (kb & 0x7FFFFFFFu) : ~kb;
        float d2v = __uint_as_float(fb);
        int e = row * KFIX + lane;
        oD[e]  = sqrtf(fmaxf(d2v, 1e-12f));
        oSA[e] = (float)(bj % N);
        oDA[e] = (float)a_i;
        oSC[e] = (float)(bj / N);
        oEV[e] = (d2v < 1e30f && c_i == CTR) ? 1.0f : 0.0f;
    }
}

// ---------------- Fallback: round-1 monolithic kernel (k != 9) ----------------
__global__ void __launch_bounds__(256) knn_kernel(
    const float* __restrict__ pos, const float* __restrict__ cell,
    const int* __restrict__ numbers, const int* __restrict__ kptr,
    float* __restrict__ out, int N)
{
    extern __shared__ float d2row[];
    const int Ns  = NSH * N;
    const int k   = kptr[0];
    const int row = blockIdx.x;
    const int tid = threadIdx.x;
    const int nthr = blockDim.x;

    __shared__ float sh_disp[NSH][3];
    __shared__ float sh_inv[3][3];
    __shared__ float sh_margin[3];
    __shared__ unsigned long long sh_wmin[4];

    if (tid == 0) cell_setup(cell, sh_disp, sh_inv, sh_margin);
    __syncthreads();

    const int a_i = row % N;
    const int c_i = row / N;
    const float pix = pos[a_i*3+0] + sh_disp[c_i][0];
    const float piy = pos[a_i*3+1] + sh_disp[c_i][1];
    const float piz = pos[a_i*3+2] + sh_disp[c_i][2];
    float sqi = pix*pix; sqi += piy*piy; sqi += piz*piz;

    bool vi = true;
    for (int d = 0; d < 3; ++d) {
        float f = pix*sh_inv[0][d];
        f += piy*sh_inv[1][d];
        f += piz*sh_inv[2][d];
        float m = sh_margin[d];
        vi = vi && (f >= -m) && (f <= 1.0f + m);
    }

    const long long NsK = (long long)Ns * (long long)k;
    float* oD  = out;
    float* oSA = out +     NsK;
    float* oDA = out + 2LL*NsK;
    float* oSC = out + 3LL*NsK;
    float* oEV = out + 4LL*NsK;
    float* oNS = out + 5LL*NsK;

    if (tid == 0) oNS[row] = (float)numbers[a_i];

    if (!vi) {
        if (tid < k) {
            long long e = (long long)row * k + tid;
            oD[e]  = sqrtf(1e30f);
            oSA[e] = (float)(tid % N);
            oDA[e] = (float)a_i;
            oSC[e] = (float)(tid / N);
            oEV[e] = 0.0f;
        }
        return;
    }

    {
        int aj = tid % N;
        int cj = tid / N;
        for (int j = tid; j < Ns; j += nthr) {
            float px = pos[aj*3+0] + sh_disp[cj][0];
            float py = pos[aj*3+1] + sh_disp[cj][1];
            float pz = pos[aj*3+2] + sh_disp[cj][2];
            float sqj = px*px; sqj += py*py; sqj += pz*pz;
            bool vj = true;
            for (int d = 0; d < 3; ++d) {
                float f = px*sh_inv[0][d];
                f += py*sh_inv[1][d];
                f += pz*sh_inv[2][d];
                float m = sh_margin[d];
                vj = vj && (f >= -m) && (f <= 1.0f + m);
            }
            float dot = pix*px; dot += piy*py; dot += piz*pz;
            float d2 = (sqi + sqj) - 2.0f*dot;
            d2row[j] = vj ? d2 : 1e30f;
            aj += nthr;
            while (aj >= N) { aj -= N; ++cj; }
        }
    }
    __syncthreads();

    const int lane = tid & 63;
    const int wid  = tid >> 6;
    const int nw   = nthr >> 6;

    for (int s = 0; s < k; ++s) {
        unsigned long long best = 0xFFFFFFFFFFFFFFFFull;
        for (int j = tid; j < Ns; j += nthr) {
            unsigned long long key = packKey(d2row[j], j);
            best = key < best ? key : best;
        }
        for (int off = 32; off > 0; off >>= 1) {
            unsigned long long o = __shfl_down(best, off, 64);
            best = o < best ? o : best;
        }
        if (lane == 0) sh_wmin[wid] = best;
        __syncthreads();
        if (tid == 0) {
            unsigned long long b = sh_wmin[0];
            for (int w = 1; w < nw; ++w) {
                unsigned long long o = sh_wmin[w];
                b = o < b ? o : b;
            }
            int bj = (int)(b & 0xFFFFFFFFull);
            d2row[bj] = INFINITY;
            unsigned int kb = (unsigned int)(b >> 32);
            unsigned int fb = (kb & 0x80000000u) ? (kb & 0x7FFFFFFFu) : ~kb;
            float d2v = __uint_as_float(fb);
            long long e = (long long)row * k + s;
            oD[e]  = sqrtf(fmaxf(d2v, 1e-12f));
            oSA[e] = (float)(bj % N);
            oDA[e] = (float)a_i;
            oSC[e] = (float)(bj / N);
            oEV[e] = (d2v < 1e30f && c_i == CTR) ? 1.0f : 0.0f;
        }
        __syncthreads();
    }
}

extern "C" void kernel_launch(void* const* d_in, const int* in_sizes, int n_in,
                              void* d_out, int out_size, void* d_ws, size_t ws_size,
                              hipStream_t stream) {
    const float* pos     = (const float*)d_in[0];   // [N,3] f32
    const float* cell    = (const float*)d_in[1];   // [3,3] f32
    const int*   numbers = (const int*)d_in[2];     // [N]   i32
    const int*   kptr    = (const int*)d_in[3];     // scalar i32
    float* out = (float*)d_out;

    const int N  = in_sizes[0] / 3;
    const int Ns = NSH * N;
    // out layout: 5 sections of [Ns,k] + [Ns]  ->  k derivable on host
    const int k   = (out_size / Ns - 1) / 5;
    const int nch = (Ns + CHUNK - 1) / CHUNK;

    if (k == KFIX && N == NFIX) {
        fused1_kernel<<<256, 512, 0, stream>>>(pos, cell, numbers, out);
        return;
    }

    const size_t needFb = 256 + (size_t)nch * CHUNK * sizeof(float4);
    if (k == KFIX && nch <= 64 && ws_size >= needFb) {
        int*    cnts   = (int*)d_ws;
        float4* chunks = (float4*)((char*)d_ws + 256);
        prep_kernel<<<256, 256, 0, stream>>>(
            pos, cell, numbers, out, cnts, chunks, N, nch);
        select_kernel<<<512, 256, 0, stream>>>(out, cnts, chunks, N, nch);
    } else {
        const size_t shbytes = (size_t)Ns * sizeof(float);
        knn_kernel<<<Ns, 256, shbytes, stream>>>(pos, cell, numbers, kptr, out, N);
    }
}

// Round 8
// 19.884 us; speedup vs baseline: 6.0347x; 1.0247x over previous
//
#include <hip/hip_runtime.h>
#include <math.h>

#define NSH 27
#define CTR 13
#define KFIX 9
#define NFIX 512      // fused path requires N == 512 (bench shape)
#define GRIDF 256     // fused path grid size (fixed)
#define CAPF 2048     // fused LDS candidate capacity (expected M ~ 885)
#define CAP 2048      // fallback dense list capacity
#define CHUNK 256     // fallback per-block compaction chunk

// Monotone map f32 -> u32 so unsigned compare == float compare, then pack
// (key, idx) into u64: min over packed = lexicographic (d2 asc, idx asc),
// exactly jax.lax.top_k's tie-break (lower index first).
__device__ __forceinline__ unsigned long long packKey(float d, int idx) {
    unsigned int b = __float_as_uint(d);
    unsigned int key = (b & 0x80000000u) ? ~b : (b | 0x80000000u);
    return ((unsigned long long)key << 32) | (unsigned int)idx;
}

__device__ __forceinline__ void cell_setup(const float* __restrict__ cell,
                                           float (*sh_disp)[3], float (*sh_inv)[3],
                                           float* sh_margin) {
    float c[3][3];
    for (int r = 0; r < 3; ++r)
        for (int d = 0; d < 3; ++d) c[r][d] = cell[r*3+d];
    float rn[3];
    for (int r = 0; r < 3; ++r) {
        float s = c[r][0]*c[r][0];
        s += c[r][1]*c[r][1];
        s += c[r][2]*c[r][2];
        rn[r] = sqrtf(s);
    }
    float dx = 0.1f * fminf(rn[0], fminf(rn[1], rn[2]));
    for (int r = 0; r < 3; ++r) sh_margin[r] = dx / rn[r];
    double a00=c[0][0],a01=c[0][1],a02=c[0][2];
    double a10=c[1][0],a11=c[1][1],a12=c[1][2];
    double a20=c[2][0],a21=c[2][1],a22=c[2][2];
    double det = a00*(a11*a22-a12*a21) - a01*(a10*a22-a12*a20)
               + a02*(a10*a21-a11*a20);
    double id = 1.0/det;
    sh_inv[0][0]=(float)((a11*a22-a12*a21)*id);
    sh_inv[0][1]=(float)((a02*a21-a01*a22)*id);
    sh_inv[0][2]=(float)((a01*a12-a02*a11)*id);
    sh_inv[1][0]=(float)((a12*a20-a10*a22)*id);
    sh_inv[1][1]=(float)((a00*a22-a02*a20)*id);
    sh_inv[1][2]=(float)((a02*a10-a00*a12)*id);
    sh_inv[2][0]=(float)((a10*a21-a11*a20)*id);
    sh_inv[2][1]=(float)((a01*a20-a00*a21)*id);
    sh_inv[2][2]=(float)((a00*a11-a01*a10)*id);
    for (int s = 0; s < NSH; ++s) {
        int ix = s/9 - 1, iy = (s/3)%3 - 1, iz = s%3 - 1;
        for (int d = 0; d < 3; ++d) {
            float v = (float)ix * c[0][d];
            v += (float)iy * c[1][d];
            v += (float)iz * c[2][d];
            sh_disp[s][d] = v;
        }
    }
}

// ===== Single fused kernel (N==512, k==9): ballot build + fill + select =====
// Wave roles after the list barrier: waves 0-3 select (one row per wave,
// block-major so 1 busy wave per SIMD machine-wide); waves 4-7 default-fill.
__global__ void __launch_bounds__(512) fused1_kernel(
    const float* __restrict__ pos, const float* __restrict__ cell,
    const int* __restrict__ numbers, float* __restrict__ out)
{
    __shared__ float4 list[CAPF];
    __shared__ unsigned int bmask[NFIX];  // bit q of bmask[t]: valid(j=q*512+t)
    __shared__ float sh_disp[NSH][3];
    __shared__ float sh_inv[3][3];
    __shared__ float sh_margin[3];
    __shared__ int wtot[8];

    const int tid  = threadIdx.x;          // == atom id t
    const int lane = tid & 63;
    const int wid  = tid >> 6;
    const int bid  = blockIdx.x;

    if (tid == 0) cell_setup(cell, sh_disp, sh_inv, sh_margin);
    __syncthreads();                       // barrier A: cell tables ready

    const int N  = NFIX;
    const int Ns = NSH * N;

    // ---- pass 1: validity bits for this thread's 27 images ----
    const float px = pos[tid*3+0];
    const float py = pos[tid*3+1];
    const float pz = pos[tid*3+2];
    unsigned int mask = 0u;
    for (int q = 0; q < NSH; ++q) {
        float x = px + sh_disp[q][0];
        float y = py + sh_disp[q][1];
        float z = pz + sh_disp[q][2];
        bool vj = true;
        for (int d = 0; d < 3; ++d) {
            float f = x*sh_inv[0][d];
            f += y*sh_inv[1][d];
            f += z*sh_inv[2][d];
            float m = sh_margin[d];
            vj = vj && (f >= -m) && (f <= 1.0f + m);
        }
        if (vj) mask |= (1u << q);
    }
    bmask[tid] = mask;
    const int cntv = __popc(mask);
    int inc = cntv;                        // inclusive lane scan
    #pragma unroll
    for (int off = 1; off < 64; off <<= 1) {
        int o = __shfl_up(inc, off, 64);
        if (lane >= off) inc += o;
    }
    if (lane == 63) wtot[wid] = inc;
    const int excl = inc - cntv;
    __syncthreads();                       // barrier B: wtot + bmask ready

    int wbase = 0;
    for (int w = 0; w < wid; ++w) wbase += wtot[w];
    int M = 0;
    for (int w = 0; w < 8; ++w) M += wtot[w];
    if (M > CAPF) M = CAPF;

    // ---- pass 2: write compacted candidate list (deterministic order) ----
    {
        int off = wbase + excl;
        for (int q = 0; q < NSH; ++q) {
            if (mask & (1u << q)) {
                if (off < CAPF) {
                    float x = px + sh_disp[q][0];
                    float y = py + sh_disp[q][1];
                    float z = pz + sh_disp[q][2];
                    list[off] = make_float4(x, y, z, __int_as_float(q*N + tid));
                }
                ++off;
            }
        }
    }
    __syncthreads();                       // barrier C: list ready

    const int NsK = Ns * KFIX;
    float* oD  = out;
    float* oSA = out +     NsK;
    float* oDA = out + 2LL*NsK;
    float* oSC = out + 3LL*NsK;
    float* oEV = out + 4LL*NsK;
    float* oNS = out + 5LL*NsK;

    if (wid >= 4) {
        // ---- fill waves: defaults for INVALID rows (disjoint from select) ----
        for (int e = bid * 256 + (tid - 256); e < NsK; e += GRIDF * 256) {
            int row = e / KFIX;
            if (!((bmask[row & 511] >> (row >> 9)) & 1u)) {
                int s = e - row * KFIX;
                oD[e]  = sqrtf(1e30f);
                oSA[e] = (float)(s % N);
                oDA[e] = (float)(row % N);
                oSC[e] = (float)(s / N);
                oEV[e] = 0.0f;
            }
        }
        for (int e = bid * 256 + (tid - 256); e < Ns; e += GRIDF * 256)
            oNS[e] = (float)numbers[e & 511];
        return;
    }

    // ---- select waves: block-major row assignment, one row per wave ----
    const unsigned long long UMAX = 0xFFFFFFFFFFFFFFFFull;

    for (int i = bid + GRIDF * wid; i < M; i += GRIDF * 8) {
        const float4 me = list[i];
        const int row = __float_as_int(me.w);
        const int a_i = row % N;
        const int c_i = row / N;
        float sqi = me.x*me.x; sqi += me.y*me.y; sqi += me.z*me.z;

        unsigned long long lst[KFIX];
        #pragma unroll
        for (int q = 0; q < KFIX; ++q) lst[q] = UMAX;

        for (int j = lane; j < M; j += 64) {
            float4 c = list[j];
            float sqj = c.x*c.x; sqj += c.y*c.y; sqj += c.z*c.z;
            float dot = me.x*c.x; dot += me.y*c.y; dot += me.z*c.z;
            float d2 = (sqi + sqj) - 2.0f*dot;
            unsigned long long key = packKey(d2, __float_as_int(c.w));
            if (key < lst[KFIX-1]) {
                lst[KFIX-1] = key;
                #pragma unroll
                for (int q = KFIX-1; q > 0; --q) {
                    unsigned long long a = lst[q-1], b = lst[q];
                    lst[q-1] = a < b ? a : b;
                    lst[q]   = a < b ? b : a;
                }
            }
        }

        // merge 64 sorted lists: k rounds of wave-wide min over heads
        unsigned long long mine = UMAX;
        #pragma unroll
        for (int s = 0; s < KFIX; ++s) {
            unsigned long long b = lst[0];
            #pragma unroll
            for (int off = 1; off < 64; off <<= 1) {
                unsigned long long o = __shfl_xor(b, off, 64);
                b = o < b ? o : b;
            }
            if (lst[0] == b) {             // unique: idx in low bits
                #pragma unroll
                for (int q = 0; q < KFIX-1; ++q) lst[q] = lst[q+1];
                lst[KFIX-1] = UMAX;
            }
            if (lane == s) mine = b;
        }

        if (lane < KFIX) {
            int bj = (int)(mine & 0xFFFFFFFFull);
            unsigned int kb = (unsigned int)(mine >> 32);
            unsigned int fb = (kb & 0x80000000u) ? (kb & 0x7FFFFFFFu) : ~kb;
            float d2v = __uint_as_float(fb);
            int e = row * KFIX + lane;
            oD[e]  = sqrtf(fmaxf(d2v, 1e-12f));
            oSA[e] = (float)(bj % N);
            oDA[e] = (float)a_i;
            oSC[e] = (float)(bj / N);
            oEV[e] = (d2v < 1e30f && c_i == CTR) ? 1.0f : 0.0f;
        }
    }
}

// ---- K1 (fallback): deterministic chunk compaction + default fill ----
__global__ void __launch_bounds__(256) prep_kernel(
    const float* __restrict__ pos, const float* __restrict__ cell,
    const int* __restrict__ numbers, float* __restrict__ out,
    int* __restrict__ cnts, float4* __restrict__ chunks, int N, int nch)
{
    __shared__ float sh_disp[NSH][3];
    __shared__ float sh_inv[3][3];
    __shared__ float sh_margin[3];
    __shared__ int wtot[4];
    const int tid = threadIdx.x;
    if (tid == 0) cell_setup(cell, sh_disp, sh_inv, sh_margin);
    __syncthreads();

    const int Ns  = NSH * N;
    const int NsK = Ns * KFIX;

    if ((int)blockIdx.x < nch) {
        const int j = blockIdx.x * CHUNK + tid;
        bool vj = false;
        float x = 0.f, y = 0.f, z = 0.f;
        if (j < Ns) {
            int aj = j % N, cj = j / N;
            x = pos[aj*3+0] + sh_disp[cj][0];
            y = pos[aj*3+1] + sh_disp[cj][1];
            z = pos[aj*3+2] + sh_disp[cj][2];
            vj = true;
            for (int d = 0; d < 3; ++d) {
                float f = x*sh_inv[0][d];
                f += y*sh_inv[1][d];
                f += z*sh_inv[2][d];
                float m = sh_margin[d];
                vj = vj && (f >= -m) && (f <= 1.0f + m);
            }
        }
        const int lane = tid & 63, wid = tid >> 6;
        unsigned long long mask = __ballot(vj);
        int within = __popcll(mask & ((1ull << lane) - 1ull));
        if (lane == 0) wtot[wid] = __popcll(mask);
        __syncthreads();
        int base = 0;
        for (int w = 0; w < wid; ++w) base += wtot[w];
        if (vj)
            chunks[blockIdx.x * CHUNK + base + within] =
                make_float4(x, y, z, __int_as_float(j));
        if (tid == 0)
            cnts[blockIdx.x] = wtot[0] + wtot[1] + wtot[2] + wtot[3];
    }

    const int gthreads = gridDim.x * blockDim.x;
    const int gt = blockIdx.x * blockDim.x + tid;
    float* oD  = out;
    float* oSA = out +     NsK;
    float* oDA = out + 2LL*NsK;
    float* oSC = out + 3LL*NsK;
    float* oEV = out + 4LL*NsK;
    float* oNS = out + 5LL*NsK;
    for (int e = gt; e < NsK; e += gthreads) {
        int row = e / KFIX;
        int s   = e - row * KFIX;
        oD[e]  = sqrtf(1e30f);
        oSA[e] = (float)(s % N);
        oDA[e] = (float)(row % N);
        oSC[e] = (float)(s / N);
        oEV[e] = 0.0f;
    }
    for (int e = gt; e < Ns; e += gthreads) oNS[e] = (float)numbers[e % N];
}

// ---- K2 (fallback): dense LDS list + one wave per valid row, top-9 ----
__global__ void __launch_bounds__(256) select_kernel(
    float* __restrict__ out,
    const int* __restrict__ cnts, const float4* __restrict__ chunks,
    int N, int nch)
{
    __shared__ float4 list[CAP];
    __shared__ int pref[65];
    const int tid  = threadIdx.x;
    const int lane = tid & 63;
    const int wid  = tid >> 6;
    const int Ns   = NSH * N;

    if (wid == 0) {
        int c = (lane < nch) ? cnts[lane] : 0;
        int s = c;
        #pragma unroll
        for (int off = 1; off < 64; off <<= 1) {
            int o = __shfl_up(s, off, 64);
            if (lane >= off) s += o;
        }
        pref[lane + 1] = s;
        if (lane == 0) pref[0] = 0;
    }
    __syncthreads();
    const int Mfull = pref[nch];
    const int M = Mfull < CAP ? Mfull : CAP;
    if ((int)blockIdx.x * 4 >= M) return;

    for (int c = wid; c < nch; c += 4) {
        int b = pref[c];
        int cc = pref[c + 1] - b;
        for (int t = lane; t < cc; t += 64)
            if (b + t < CAP) list[b + t] = chunks[c * CHUNK + t];
    }
    __syncthreads();

    const int i = blockIdx.x * 4 + wid;
    if (i >= M) return;

    const float4 me = list[i];
    const int row = __float_as_int(me.w);
    const int a_i = row % N;
    const int c_i = row / N;
    float sqi = me.x*me.x; sqi += me.y*me.y; sqi += me.z*me.z;

    const unsigned long long UMAX = 0xFFFFFFFFFFFFFFFFull;
    unsigned long long lst[KFIX];
    #pragma unroll
    for (int q = 0; q < KFIX; ++q) lst[q] = UMAX;

    for (int j = lane; j < M; j += 64) {
        float4 c = list[j];
        float sqj = c.x*c.x; sqj += c.y*c.y; sqj += c.z*c.z;
        float dot = me.x*c.x; dot += me.y*c.y; dot += me.z*c.z;
        float d2 = (sqi + sqj) - 2.0f*dot;
        unsigned long long key = packKey(d2, __float_as_int(c.w));
        if (key < lst[KFIX-1]) {
            lst[KFIX-1] = key;
            #pragma unroll
            for (int q = KFIX-1; q > 0; --q) {
                unsigned long long a = lst[q-1], b = lst[q];
                lst[q-1] = a < b ? a : b;
                lst[q]   = a < b ? b : a;
            }
        }
    }

    unsigned long long mine = UMAX;
    #pragma unroll
    for (int s = 0; s < KFIX; ++s) {
        unsigned long long b = lst[0];
        #pragma unroll
        for (int off = 1; off < 64; off <<= 1) {
            unsigned long long o = __shfl_xor(b, off, 64);
            b = o < b ? o : b;
        }
        if (lst[0] == b) {
            #pragma unroll
            for (int q = 0; q < KFIX-1; ++q) lst[q] = lst[q+1];
            lst[KFIX-1] = UMAX;
        }
        if (lane == s) mine = b;
    }

    if (lane < KFIX) {
        const int NsK = Ns * KFIX;
        float* oD  = out;
        float* oSA = out +     NsK;
        float* oDA = out + 2LL*NsK;
        float* oSC = out + 3LL*NsK;
        float* oEV = out + 4LL*NsK;
        int bj = (int)(mine & 0xFFFFFFFFull);
        unsigned int kb = (unsigned int)(mine >> 32);
        unsigned int fb = (kb & 0x80000000u) ? (kb & 0x7FFFFFFFu) : ~kb;
        float d2v = __uint_as_float(fb);
        int e = row * KFIX + lane;
        oD[e]  = sqrtf(fmaxf(d2v, 1e-12f));
        oSA[e] = (float)(bj % N);
        oDA[e] = (float)a_i;
        oSC[e] = (float)(bj / N);
        oEV[e] = (d2v < 1e30f && c_i == CTR) ? 1.0f : 0.0f;
    }
}

// ---------------- Fallback: round-1 monolithic kernel (k != 9) ----------------
__global__ void __launch_bounds__(256) knn_kernel(
    const float* __restrict__ pos, const float* __restrict__ cell,
    const int* __restrict__ numbers, const int* __restrict__ kptr,
    float* __restrict__ out, int N)
{
    extern __shared__ float d2row[];
    const int Ns  = NSH * N;
    const int k   = kptr[0];
    const int row = blockIdx.x;
    const int tid = threadIdx.x;
    const int nthr = blockDim.x;

    __shared__ float sh_disp[NSH][3];
    __shared__ float sh_inv[3][3];
    __shared__ float sh_margin[3];
    __shared__ unsigned long long sh_wmin[4];

    if (tid == 0) cell_setup(cell, sh_disp, sh_inv, sh_margin);
    __syncthreads();

    const int a_i = row % N;
    const int c_i = row / N;
    const float pix = pos[a_i*3+0] + sh_disp[c_i][0];
    const float piy = pos[a_i*3+1] + sh_disp[c_i][1];
    const float piz = pos[a_i*3+2] + sh_disp[c_i][2];
    float sqi = pix*pix; sqi += piy*piy; sqi += piz*piz;

    bool vi = true;
    for (int d = 0; d < 3; ++d) {
        float f = pix*sh_inv[0][d];
        f += piy*sh_inv[1][d];
        f += piz*sh_inv[2][d];
        float m = sh_margin[d];
        vi = vi && (f >= -m) && (f <= 1.0f + m);
    }

    const long long NsK = (long long)Ns * (long long)k;
    float* oD  = out;
    float* oSA = out +     NsK;
    float* oDA = out + 2LL*NsK;
    float* oSC = out + 3LL*NsK;
    float* oEV = out + 4LL*NsK;
    float* oNS = out + 5LL*NsK;

    if (tid == 0) oNS[row] = (float)numbers[a_i];

    if (!vi) {
        if (tid < k) {
            long long e = (long long)row * k + tid;
            oD[e]  = sqrtf(1e30f);
            oSA[e] = (float)(tid % N);
            oDA[e] = (float)a_i;
            oSC[e] = (float)(tid / N);
            oEV[e] = 0.0f;
        }
        return;
    }

    {
        int aj = tid % N;
        int cj = tid / N;
        for (int j = tid; j < Ns; j += nthr) {
            float px = pos[aj*3+0] + sh_disp[cj][0];
            float py = pos[aj*3+1] + sh_disp[cj][1];
            float pz = pos[aj*3+2] + sh_disp[cj][2];
            float sqj = px*px; sqj += py*py; sqj += pz*pz;
            bool vj = true;
            for (int d = 0; d < 3; ++d) {
                float f = px*sh_inv[0][d];
                f += py*sh_inv[1][d];
                f += pz*sh_inv[2][d];
                float m = sh_margin[d];
                vj = vj && (f >= -m) && (f <= 1.0f + m);
            }
            float dot = pix*px; dot += piy*py; dot += piz*pz;
            float d2 = (sqi + sqj) - 2.0f*dot;
            d2row[j] = vj ? d2 : 1e30f;
            aj += nthr;
            while (aj >= N) { aj -= N; ++cj; }
        }
    }
    __syncthreads();

    const int lane = tid & 63;
    const int wid  = tid >> 6;
    const int nw   = nthr >> 6;

    for (int s = 0; s < k; ++s) {
        unsigned long long best = 0xFFFFFFFFFFFFFFFFull;
        for (int j = tid; j < Ns; j += nthr) {
            unsigned long long key = packKey(d2row[j], j);
            best = key < best ? key : best;
        }
        for (int off = 32; off > 0; off >>= 1) {
            unsigned long long o = __shfl_down(best, off, 64);
            best = o < best ? o : best;
        }
        if (lane == 0) sh_wmin[wid] = best;
        __syncthreads();
        if (tid == 0) {
            unsigned long long b = sh_wmin[0];
            for (int w = 1; w < nw; ++w) {
                unsigned long long o = sh_wmin[w];
                b = o < b ? o : b;
            }
            int bj = (int)(b & 0xFFFFFFFFull);
            d2row[bj] = INFINITY;
            unsigned int kb = (unsigned int)(b >> 32);
            unsigned int fb = (kb & 0x80000000u) ? (kb & 0x7FFFFFFFu) : ~kb;
            float d2v = __uint_as_float(fb);
            long long e = (long long)row * k + s;
            oD[e]  = sqrtf(fmaxf(d2v, 1e-12f));
            oSA[e] = (float)(bj % N);
            oDA[e] = (float)a_i;
            oSC[e] = (float)(bj / N);
            oEV[e] = (d2v < 1e30f && c_i == CTR) ? 1.0f : 0.0f;
        }
        __syncthreads();
    }
}

extern "C" void kernel_launch(void* const* d_in, const int* in_sizes, int n_in,
                              void* d_out, int out_size, void* d_ws, size_t ws_size,
                              hipStream_t stream) {
    const float* pos     = (const float*)d_in[0];   // [N,3] f32
    const float* cell    = (const float*)d_in[1];   // [3,3] f32
    const int*   numbers = (const int*)d_in[2];     // [N]   i32
    const int*   kptr    = (const int*)d_in[3];     // scalar i32
    float* out = (float*)d_out;

    const int N  = in_sizes[0] / 3;
    const int Ns = NSH * N;
    // out layout: 5 sections of [Ns,k] + [Ns]  ->  k derivable on host
    const int k   = (out_size / Ns - 1) / 5;
    const int nch = (Ns + CHUNK - 1) / CHUNK;

    if (k == KFIX && N == NFIX) {
        fused1_kernel<<<GRIDF, 512, 0, stream>>>(pos, cell, numbers, out);
        return;
    }

    const size_t needFb = 256 + (size_t)nch * CHUNK * sizeof(float4);
    if (k == KFIX && nch <= 64 && ws_size >= needFb) {
        int*    cnts   = (int*)d_ws;
        float4* chunks = (float4*)((char*)d_ws + 256);
        prep_kernel<<<256, 256, 0, stream>>>(
            pos, cell, numbers, out, cnts, chunks, N, nch);
        select_kernel<<<512, 256, 0, stream>>>(out, cnts, chunks, N, nch);
    } else {
        const size_t shbytes = (size_t)Ns * sizeof(float);
        knn_kernel<<<Ns, 256, shbytes, stream>>>(pos, cell, numbers, kptr, out, N);
    }
}